// Round 7
// baseline (941.988 us; speedup 1.0000x reference)
//
#include <hip/hip_runtime.h>
#include <math.h>

// InstantNGP-style hash-grid encoder, 16 levels, FEAT=2, B=2M points.
//   dense levels 0..4 (res^3 <= 2^19), hashed levels 5..15 (size = 2^19 each)
//
// Measured model (r3-r6): fully-divergent gathers are TA-bound at ~127 cyc per
// wave-instruction for 8B/lane (~2 cyc/lane-request); 16B costs ~1.5x; active-
// lane masking does NOT reduce cost (r6); pairing tricks with divergent fixup
// branches are net losses. This round probes 4B/lane scaling:
//   - fine levels: 8 plain 4B gathers from a bf16x2-converted table
//     (converted once per launch into ws; 2MB slice per level, L2-fit).
//   - dense levels: unchanged f32 16B x-paired loads (known 161us).
//   - ws staging bf16x2; merge pure streaming.
#define NLEVELS 16
#define BEGIN_FAST 5
#define P2 2654435761u
#define P3 805459861u
#define FAST_MASK 524287u  // size = 2^19 for all hashed levels
#define TOTAL_ENTRIES 6098120u

constexpr unsigned kRes[NLEVELS] = {16u, 23u, 31u, 43u, 59u, 81u, 112u, 154u, 213u, 295u, 407u, 562u, 777u, 1073u, 1483u, 2048u};
constexpr unsigned kSize[NLEVELS] = {
    4096u, 12168u, 29792u, 79512u, 205384u,
    524288u, 524288u, 524288u, 524288u, 524288u, 524288u,
    524288u, 524288u, 524288u, 524288u, 524288u};
constexpr unsigned kOffset[NLEVELS] = {
    0u,       4096u,    16264u,   46056u,   125568u,  330952u,
    855240u,  1379528u, 1903816u, 2428104u, 2952392u, 3476680u,
    4000968u, 4525256u, 5049544u, 5573832u};

struct Scales {
    float s[NLEVELS];
};

typedef float fvec4 __attribute__((ext_vector_type(4)));
typedef float fvec4a8 __attribute__((ext_vector_type(4), aligned(8)));
typedef unsigned uvec2 __attribute__((ext_vector_type(2)));

// pack two f32 -> bf16x2 (round-to-nearest-even), lo = a, hi = b
__device__ __forceinline__ unsigned bfpack(float a, float b) {
    unsigned ua = __float_as_uint(a);
    unsigned ub = __float_as_uint(b);
    ua = (ua + 0x7FFFu + ((ua >> 16) & 1u)) >> 16;
    ub = (ub + 0x7FFFu + ((ub >> 16) & 1u)) & 0xFFFF0000u;
    return ua | ub;
}
__device__ __forceinline__ float bf_lo(unsigned e) { return __uint_as_float(e << 16); }
__device__ __forceinline__ float bf_hi(unsigned e) { return __uint_as_float(e & 0xFFFF0000u); }

// --------- convert: f32 table -> bf16x2 entries (4B per entry) ---------------
__global__ __launch_bounds__(256) void convert_kernel(
    const fvec4* __restrict__ t4,   // table viewed as 2 entries per 16B
    uvec2* __restrict__ bt,         // bf16 table viewed as 2 entries per 8B
    int npairs)
{
    int j = blockIdx.x * 256 + threadIdx.x;
    if (j >= npairs) return;
    const fvec4 v = __builtin_nontemporal_load(t4 + j);
    uvec2 r = {bfpack(v.x, v.y), bfpack(v.z, v.w)};
    __builtin_nontemporal_store(r, bt + j);
}

// ---------------- fine (hashed) level: bf16 slice, 2MB, L2-fit ---------------
__global__ __launch_bounds__(256) void fine_level_kernel(
    const float* __restrict__ positions,  // [B,3]
    const unsigned* __restrict__ bt,      // bf16x2 table + kOffset[l]
    unsigned* __restrict__ wsl,           // ws slice [B], bf16x2 packed
    int B, float s)
{
    int p = blockIdx.x * 256 + threadIdx.x;
    if (p >= B) return;

    const float x = __builtin_nontemporal_load(positions + 3 * p + 0);
    const float y = __builtin_nontemporal_load(positions + 3 * p + 1);
    const float z = __builtin_nontemporal_load(positions + 3 * p + 2);

    const float px = x * s + 0.5f;
    const float py = y * s + 0.5f;
    const float pz = z * s + 0.5f;
    const float flx = floorf(px), fly = floorf(py), flz = floorf(pz);
    const float rx = px - flx, ry = py - fly, rz = pz - flz;
    const unsigned gx = (unsigned)flx;
    const unsigned gy = (unsigned)fly;
    const unsigned gz = (unsigned)flz;
    const float wx0 = 1.0f - rx, wy0 = 1.0f - ry, wz0 = 1.0f - rz;

    const unsigned hy0 = gy * P2, hy1 = hy0 + P2;
    const unsigned hz0 = gz * P3, hz1 = hz0 + P3;

    float ax = 0.0f, ay = 0.0f;
#pragma unroll
    for (int c = 0; c < 8; ++c) {
        const unsigned cx = (unsigned)(c & 1);
        const unsigned cy = (unsigned)((c >> 1) & 1);
        const unsigned cz = (unsigned)((c >> 2) & 1);
        const float w = (cx ? rx : wx0) * (cy ? ry : wy0) * (cz ? rz : wz0);
        const unsigned h = (gx + cx) ^ (cy ? hy1 : hy0) ^ (cz ? hz1 : hz0);
        const unsigned e = bt[h & FAST_MASK];     // 4B divergent gather
        ax += w * bf_lo(e);
        ay += w * bf_hi(e);
    }
    __builtin_nontemporal_store(bfpack(ax, ay), wsl + p);
}

// ---------------- dense levels 0..4 -> ws slices 0..4 (f32 table) ------------
__global__ __launch_bounds__(256) void dense_kernel(
    const float* __restrict__ positions,  // [B,3]
    const float2* __restrict__ table,     // full f32 table
    unsigned* __restrict__ ws,            // slices [16][B]; writes 0..4
    int B, Scales sc)
{
    int p = blockIdx.x * 256 + threadIdx.x;
    if (p >= B) return;

    const float x = __builtin_nontemporal_load(positions + 3 * p + 0);
    const float y = __builtin_nontemporal_load(positions + 3 * p + 1);
    const float z = __builtin_nontemporal_load(positions + 3 * p + 2);

#pragma unroll
    for (int l = 0; l < BEGIN_FAST; ++l) {
        const float s = sc.s[l];
        const float px = x * s + 0.5f;
        const float py = y * s + 0.5f;
        const float pz = z * s + 0.5f;
        const float flx = floorf(px), fly = floorf(py), flz = floorf(pz);
        const float rx = px - flx, ry = py - fly, rz = pz - flz;
        const unsigned gx = (unsigned)flx;
        const unsigned gy = (unsigned)fly;
        const unsigned gz = (unsigned)flz;
        const float wx0 = 1.0f - rx, wy0 = 1.0f - ry, wz0 = 1.0f - rz;

        const float2* tab = table + kOffset[l];
        const unsigned res = kRes[l];

        float ax = 0.0f, ay = 0.0f;
#pragma unroll
        for (int cc = 0; cc < 4; ++cc) {          // (cy, cz); x-pair fused
            const unsigned cy = (unsigned)(cc & 1);
            const unsigned cz = (unsigned)(cc >> 1);
            const float wyz = (cy ? ry : wy0) * (cz ? rz : wz0);
            const unsigned h0 = gx + (gy + cy) * res + (gz + cz) * (res * res);
            const unsigned idx0 = h0 % kSize[l];
            const fvec4 tt = *reinterpret_cast<const fvec4a8*>(tab + idx0);
            float t1x = tt.z, t1y = tt.w;
            if (idx0 == kSize[l] - 1) {           // (h0+1) % size wrapped to 0
                const float2 tf = tab[0];
                t1x = tf.x; t1y = tf.y;
            }
            ax += wyz * (wx0 * tt.x + rx * t1x);
            ay += wyz * (wx0 * tt.y + rx * t1y);
        }
        __builtin_nontemporal_store(bfpack(ax, ay), ws + (size_t)l * (size_t)B + p);
    }
}

// ---------------- merge: pure streaming, no gathers --------------------------
__global__ __launch_bounds__(256) void merge_kernel(
    const unsigned* __restrict__ ws,  // [16][B] bf16x2 packed
    float* __restrict__ out,          // [B,32]
    int B)
{
    int p = blockIdx.x * 256 + threadIdx.x;
    if (p >= B) return;

    float o[2 * NLEVELS];
#pragma unroll
    for (int l = 0; l < NLEVELS; ++l) {
        const unsigned v = __builtin_nontemporal_load(ws + (size_t)l * (size_t)B + p);
        o[2 * l + 0] = bf_lo(v);
        o[2 * l + 1] = bf_hi(v);
    }
    float* op = out + (size_t)p * (2 * NLEVELS);
#pragma unroll
    for (int i = 0; i < 8; ++i) {
        fvec4 v = {o[4 * i + 0], o[4 * i + 1], o[4 * i + 2], o[4 * i + 3]};
        *(reinterpret_cast<fvec4*>(op) + i) = v;
    }
}

// ---------------- fallback: monolithic f32 (if ws too small) -----------------
__global__ __launch_bounds__(256) void hash_encode_kernel(
    const float* __restrict__ positions,
    const float2* __restrict__ table,
    float* __restrict__ out,
    int B, Scales sc)
{
    int p = blockIdx.x * 256 + threadIdx.x;
    if (p >= B) return;

    const float x = positions[3 * p + 0];
    const float y = positions[3 * p + 1];
    const float z = positions[3 * p + 2];

    float o[2 * NLEVELS];

#pragma unroll
    for (int l = 0; l < NLEVELS; ++l) {
        const float s = sc.s[l];
        const float px = x * s + 0.5f;
        const float py = y * s + 0.5f;
        const float pz = z * s + 0.5f;
        const float flx = floorf(px), fly = floorf(py), flz = floorf(pz);
        const float rx = px - flx, ry = py - fly, rz = pz - flz;
        const unsigned gx = (unsigned)flx;
        const unsigned gy = (unsigned)fly;
        const unsigned gz = (unsigned)flz;
        const float wx0 = 1.0f - rx, wy0 = 1.0f - ry, wz0 = 1.0f - rz;

        float ax = 0.0f, ay = 0.0f;
#pragma unroll
        for (int c = 0; c < 8; ++c) {
            const unsigned cx = (unsigned)(c & 1);
            const unsigned cy = (unsigned)((c >> 1) & 1);
            const unsigned cz = (unsigned)((c >> 2) & 1);
            const unsigned pgx = gx + cx;
            const unsigned pgy = gy + cy;
            const unsigned pgz = gz + cz;
            const float w = (cx ? rx : wx0) * (cy ? ry : wy0) * (cz ? rz : wz0);
            unsigned h;
            if (l < BEGIN_FAST) {
                h = pgx + pgy * kRes[l] + pgz * (kRes[l] * kRes[l]);
            } else {
                h = pgx ^ (pgy * P2) ^ (pgz * P3);
            }
            const unsigned idx = (h % kSize[l]) + kOffset[l];
            const float2 t = table[idx];
            ax += w * t.x;
            ay += w * t.y;
        }
        o[2 * l + 0] = ax;
        o[2 * l + 1] = ay;
    }

    float* op = out + (size_t)p * (2 * NLEVELS);
#pragma unroll
    for (int i = 0; i < 8; ++i) {
        fvec4 v = {o[4 * i + 0], o[4 * i + 1], o[4 * i + 2], o[4 * i + 3]};
        *(reinterpret_cast<fvec4*>(op) + i) = v;
    }
}

extern "C" void kernel_launch(void* const* d_in, const int* in_sizes, int n_in,
                              void* d_out, int out_size, void* d_ws, size_t ws_size,
                              hipStream_t stream) {
    const float* positions = (const float*)d_in[0];
    const float2* table = (const float2*)d_in[1];
    float* out = (float*)d_out;

    const int B = in_sizes[0] / 3;

    Scales sc;
    const double log_b = log(2048.0 / 16.0) / (NLEVELS - 1);
    for (int l = 0; l < NLEVELS; ++l) {
        sc.s[l] = (float)(16.0 * exp((double)l * log_b) - 1.0);
    }

    const int blocks = (B + 255) / 256;
    const int npairs = (int)(TOTAL_ENTRIES / 2u);           // 3,049,060
    const size_t slices_bytes = (size_t)NLEVELS * (size_t)B * sizeof(unsigned);
    const size_t bt_bytes = (size_t)TOTAL_ENTRIES * sizeof(unsigned); // 24.4 MB
    const size_t ws_need = slices_bytes + bt_bytes;

    if (ws_size >= ws_need) {
        unsigned* ws = (unsigned*)d_ws;                      // 16 slices [B]
        unsigned* bt = (unsigned*)((char*)d_ws + slices_bytes); // bf16x2 table

        convert_kernel<<<(npairs + 255) / 256, 256, 0, stream>>>(
            (const fvec4*)table, (uvec2*)bt, npairs);

        for (int l = BEGIN_FAST; l < NLEVELS; ++l) {
            fine_level_kernel<<<blocks, 256, 0, stream>>>(
                positions, bt + kOffset[l],
                ws + (size_t)l * (size_t)B, B, sc.s[l]);
        }
        dense_kernel<<<blocks, 256, 0, stream>>>(positions, table, ws, B, sc);
        merge_kernel<<<blocks, 256, 0, stream>>>(ws, out, B);
    } else {
        hash_encode_kernel<<<blocks, 256, 0, stream>>>(positions, table, out, B, sc);
    }
}

// Round 8
// 817.513 us; speedup vs baseline: 1.1523x; 1.1523x over previous
//
#include <hip/hip_runtime.h>
#include <math.h>

// InstantNGP-style hash-grid encoder, 16 levels, FEAT=2, B=2M points.
//   dense levels 0..4 (res^3 <= 2^19), hashed levels 5..15 (size = 2^19 each)
//
// Measured model (r3-r7): divergent gathers cost ~128 cyc per wave-instruction
// at <=8B/lane (~1.5x at 16B), regardless of cache level, active-lane count,
// or 4B-vs-8B width. Best fine config (51.6us/level): plain 8x 8B f32 gathers
// from the pristine input table + 8B float2 NT ws store. Dense improvement:
// redundant PAIRED bf16 table E[j]=(T[j],T[(j+1)%size]) -> x-pair in ONE 8B
// load, 4 loads/level (was 4x16B), no fixup ever.
#define NLEVELS 16
#define BEGIN_FAST 5
#define P2 2654435761u
#define P3 805459861u
#define FAST_MASK 524287u
#define DENSE_TOTAL 330952u

constexpr unsigned kRes[NLEVELS] = {16u, 23u, 31u, 43u, 59u, 81u, 112u, 154u, 213u, 295u, 407u, 562u, 777u, 1073u, 1483u, 2048u};
constexpr unsigned kSize[NLEVELS] = {
    4096u, 12168u, 29792u, 79512u, 205384u,
    524288u, 524288u, 524288u, 524288u, 524288u, 524288u,
    524288u, 524288u, 524288u, 524288u, 524288u};
constexpr unsigned kOffset[NLEVELS] = {
    0u,       4096u,    16264u,   46056u,   125568u,  330952u,
    855240u,  1379528u, 1903816u, 2428104u, 2952392u, 3476680u,
    4000968u, 4525256u, 5049544u, 5573832u};

struct Scales {
    float s[NLEVELS];
};

typedef float fvec2 __attribute__((ext_vector_type(2)));
typedef float fvec4 __attribute__((ext_vector_type(4)));
typedef unsigned uvec2 __attribute__((ext_vector_type(2)));

// pack two f32 -> bf16x2 (round-to-nearest-even), lo = a, hi = b
__device__ __forceinline__ unsigned bfpack(float a, float b) {
    unsigned ua = __float_as_uint(a);
    unsigned ub = __float_as_uint(b);
    ua = (ua + 0x7FFFu + ((ua >> 16) & 1u)) >> 16;
    ub = (ub + 0x7FFFu + ((ub >> 16) & 1u)) & 0xFFFF0000u;
    return ua | ub;
}
__device__ __forceinline__ float bf_lo(unsigned e) { return __uint_as_float(e << 16); }
__device__ __forceinline__ float bf_hi(unsigned e) { return __uint_as_float(e & 0xFFFF0000u); }

// ---- convert dense tables to paired bf16: E[j] = (Tbf[j], Tbf[(j+1)%size]) --
__global__ __launch_bounds__(256) void convert_dense_kernel(
    const float2* __restrict__ table,  // full f32 table
    uvec2* __restrict__ E,             // paired bf16 dense table [DENSE_TOTAL]
    int total)
{
    int j = blockIdx.x * 256 + threadIdx.x;
    if (j >= total) return;
    // find level (5 compile-time boundaries)
    int l = 0;
    if (j >= (int)kOffset[1]) l = 1;
    if (j >= (int)kOffset[2]) l = 2;
    if (j >= (int)kOffset[3]) l = 3;
    if (j >= (int)kOffset[4]) l = 4;
    const unsigned jl = (unsigned)j - kOffset[l];
    const unsigned jn = (jl + 1u == kSize[l]) ? 0u : jl + 1u;
    const float2 t0 = table[kOffset[l] + jl];
    const float2 t1 = table[kOffset[l] + jn];
    uvec2 r = {bfpack(t0.x, t0.y), bfpack(t1.x, t1.y)};
    __builtin_nontemporal_store(r, E + j);
}

// ---------------- fine (hashed) level: EXACT r3 51.6us config ----------------
__global__ __launch_bounds__(256) void fine_level_kernel(
    const float* __restrict__ positions,  // [B,3]
    const float2* __restrict__ tab,       // f32 table + level offset
    float2* __restrict__ wsl,             // ws slice [B], float2
    int B, float s)
{
    int p = blockIdx.x * 256 + threadIdx.x;
    if (p >= B) return;

    const float x = __builtin_nontemporal_load(positions + 3 * p + 0);
    const float y = __builtin_nontemporal_load(positions + 3 * p + 1);
    const float z = __builtin_nontemporal_load(positions + 3 * p + 2);

    const float px = x * s + 0.5f;
    const float py = y * s + 0.5f;
    const float pz = z * s + 0.5f;
    const float flx = floorf(px), fly = floorf(py), flz = floorf(pz);
    const float rx = px - flx, ry = py - fly, rz = pz - flz;
    const unsigned gx = (unsigned)flx;
    const unsigned gy = (unsigned)fly;
    const unsigned gz = (unsigned)flz;
    const float wx0 = 1.0f - rx, wy0 = 1.0f - ry, wz0 = 1.0f - rz;

    const unsigned hy0 = gy * P2, hy1 = hy0 + P2;
    const unsigned hz0 = gz * P3, hz1 = hz0 + P3;

    float ax = 0.0f, ay = 0.0f;
#pragma unroll
    for (int c = 0; c < 8; ++c) {
        const unsigned cx = (unsigned)(c & 1);
        const unsigned cy = (unsigned)((c >> 1) & 1);
        const unsigned cz = (unsigned)((c >> 2) & 1);
        const float w = (cx ? rx : wx0) * (cy ? ry : wy0) * (cz ? rz : wz0);
        const unsigned h = (gx + cx) ^ (cy ? hy1 : hy0) ^ (cz ? hz1 : hz0);
        const float2 t = tab[h & FAST_MASK];
        ax += w * t.x;
        ay += w * t.y;
    }
    fvec2 r = {ax, ay};
    __builtin_nontemporal_store(r, reinterpret_cast<fvec2*>(wsl) + p);
}

// ------- dense levels 0..4 via paired bf16 table: 4x 8B gathers/level --------
__global__ __launch_bounds__(256) void dense_kernel(
    const float* __restrict__ positions,  // [B,3]
    const uvec2* __restrict__ E,          // paired bf16 dense table
    unsigned* __restrict__ dws,           // dense ws slices [5][B], bf16x2
    int B, Scales sc)
{
    int p = blockIdx.x * 256 + threadIdx.x;
    if (p >= B) return;

    const float x = __builtin_nontemporal_load(positions + 3 * p + 0);
    const float y = __builtin_nontemporal_load(positions + 3 * p + 1);
    const float z = __builtin_nontemporal_load(positions + 3 * p + 2);

#pragma unroll
    for (int l = 0; l < BEGIN_FAST; ++l) {
        const float s = sc.s[l];
        const float px = x * s + 0.5f;
        const float py = y * s + 0.5f;
        const float pz = z * s + 0.5f;
        const float flx = floorf(px), fly = floorf(py), flz = floorf(pz);
        const float rx = px - flx, ry = py - fly, rz = pz - flz;
        const unsigned gx = (unsigned)flx;
        const unsigned gy = (unsigned)fly;
        const unsigned gz = (unsigned)flz;
        const float wx0 = 1.0f - rx, wy0 = 1.0f - ry, wz0 = 1.0f - rz;

        const uvec2* tab = E + kOffset[l];
        const unsigned res = kRes[l];

        float ax = 0.0f, ay = 0.0f;
#pragma unroll
        for (int cc = 0; cc < 4; ++cc) {          // (cy, cz); x-pair in one 8B
            const unsigned cy = (unsigned)(cc & 1);
            const unsigned cz = (unsigned)(cc >> 1);
            const float wyz = (cy ? ry : wy0) * (cz ? rz : wz0);
            const unsigned h0 = gx + (gy + cy) * res + (gz + cz) * (res * res);
            const unsigned idx0 = h0 % kSize[l];
            const uvec2 q = tab[idx0];            // (corner0, corner1) bf16x2
            ax += wyz * (wx0 * bf_lo(q.x) + rx * bf_lo(q.y));
            ay += wyz * (wx0 * bf_hi(q.x) + rx * bf_hi(q.y));
        }
        __builtin_nontemporal_store(bfpack(ax, ay), dws + (size_t)l * (size_t)B + p);
    }
}

// ---------------- merge: pure streaming, no gathers --------------------------
__global__ __launch_bounds__(256) void merge_kernel(
    const unsigned* __restrict__ dws,  // [5][B] bf16x2
    const float2* __restrict__ fws,    // [11][B] float2
    float* __restrict__ out,           // [B,32]
    int B)
{
    int p = blockIdx.x * 256 + threadIdx.x;
    if (p >= B) return;

    float o[2 * NLEVELS];
#pragma unroll
    for (int l = 0; l < BEGIN_FAST; ++l) {
        const unsigned v = __builtin_nontemporal_load(dws + (size_t)l * (size_t)B + p);
        o[2 * l + 0] = bf_lo(v);
        o[2 * l + 1] = bf_hi(v);
    }
#pragma unroll
    for (int l = BEGIN_FAST; l < NLEVELS; ++l) {
        const fvec2 v = __builtin_nontemporal_load(
            reinterpret_cast<const fvec2*>(fws) + (size_t)(l - BEGIN_FAST) * (size_t)B + p);
        o[2 * l + 0] = v.x;
        o[2 * l + 1] = v.y;
    }
    float* op = out + (size_t)p * (2 * NLEVELS);
#pragma unroll
    for (int i = 0; i < 8; ++i) {
        fvec4 v = {o[4 * i + 0], o[4 * i + 1], o[4 * i + 2], o[4 * i + 3]};
        *(reinterpret_cast<fvec4*>(op) + i) = v;
    }
}

// ---------------- fallback: monolithic f32 (if ws too small) -----------------
__global__ __launch_bounds__(256) void hash_encode_kernel(
    const float* __restrict__ positions,
    const float2* __restrict__ table,
    float* __restrict__ out,
    int B, Scales sc)
{
    int p = blockIdx.x * 256 + threadIdx.x;
    if (p >= B) return;

    const float x = positions[3 * p + 0];
    const float y = positions[3 * p + 1];
    const float z = positions[3 * p + 2];

    float o[2 * NLEVELS];

#pragma unroll
    for (int l = 0; l < NLEVELS; ++l) {
        const float s = sc.s[l];
        const float px = x * s + 0.5f;
        const float py = y * s + 0.5f;
        const float pz = z * s + 0.5f;
        const float flx = floorf(px), fly = floorf(py), flz = floorf(pz);
        const float rx = px - flx, ry = py - fly, rz = pz - flz;
        const unsigned gx = (unsigned)flx;
        const unsigned gy = (unsigned)fly;
        const unsigned gz = (unsigned)flz;
        const float wx0 = 1.0f - rx, wy0 = 1.0f - ry, wz0 = 1.0f - rz;

        float ax = 0.0f, ay = 0.0f;
#pragma unroll
        for (int c = 0; c < 8; ++c) {
            const unsigned cx = (unsigned)(c & 1);
            const unsigned cy = (unsigned)((c >> 1) & 1);
            const unsigned cz = (unsigned)((c >> 2) & 1);
            const unsigned pgx = gx + cx;
            const unsigned pgy = gy + cy;
            const unsigned pgz = gz + cz;
            const float w = (cx ? rx : wx0) * (cy ? ry : wy0) * (cz ? rz : wz0);
            unsigned h;
            if (l < BEGIN_FAST) {
                h = pgx + pgy * kRes[l] + pgz * (kRes[l] * kRes[l]);
            } else {
                h = pgx ^ (pgy * P2) ^ (pgz * P3);
            }
            const unsigned idx = (h % kSize[l]) + kOffset[l];
            const float2 t = table[idx];
            ax += w * t.x;
            ay += w * t.y;
        }
        o[2 * l + 0] = ax;
        o[2 * l + 1] = ay;
    }

    float* op = out + (size_t)p * (2 * NLEVELS);
#pragma unroll
    for (int i = 0; i < 8; ++i) {
        fvec4 v = {o[4 * i + 0], o[4 * i + 1], o[4 * i + 2], o[4 * i + 3]};
        *(reinterpret_cast<fvec4*>(op) + i) = v;
    }
}

extern "C" void kernel_launch(void* const* d_in, const int* in_sizes, int n_in,
                              void* d_out, int out_size, void* d_ws, size_t ws_size,
                              hipStream_t stream) {
    const float* positions = (const float*)d_in[0];
    const float2* table = (const float2*)d_in[1];
    float* out = (float*)d_out;

    const int B = in_sizes[0] / 3;

    Scales sc;
    const double log_b = log(2048.0 / 16.0) / (NLEVELS - 1);
    for (int l = 0; l < NLEVELS; ++l) {
        sc.s[l] = (float)(16.0 * exp((double)l * log_b) - 1.0);
    }

    const int blocks = (B + 255) / 256;

    // ws layout: [5 dense slices, 4B each][11 fine slices, 8B each][paired E]
    const size_t dws_bytes = 5u * (size_t)B * sizeof(unsigned);       // 40 MB
    const size_t fws_bytes = 11u * (size_t)B * sizeof(float2);        // 176 MB
    const size_t E_bytes = (size_t)DENSE_TOTAL * sizeof(uvec2);       // 2.65 MB
    const size_t ws_need = dws_bytes + fws_bytes + E_bytes;

    if (ws_size >= ws_need) {
        unsigned* dws = (unsigned*)d_ws;
        float2* fws = (float2*)((char*)d_ws + dws_bytes);
        uvec2* E = (uvec2*)((char*)d_ws + dws_bytes + fws_bytes);

        convert_dense_kernel<<<((int)DENSE_TOTAL + 255) / 256, 256, 0, stream>>>(
            table, E, (int)DENSE_TOTAL);

        for (int l = BEGIN_FAST; l < NLEVELS; ++l) {
            fine_level_kernel<<<blocks, 256, 0, stream>>>(
                positions, table + kOffset[l],
                fws + (size_t)(l - BEGIN_FAST) * (size_t)B, B, sc.s[l]);
        }
        dense_kernel<<<blocks, 256, 0, stream>>>(positions, E, dws, B, sc);
        merge_kernel<<<blocks, 256, 0, stream>>>(dws, fws, out, B);
    } else {
        hash_encode_kernel<<<blocks, 256, 0, stream>>>(positions, table, out, B, sc);
    }
}

// Round 9
// 812.073 us; speedup vs baseline: 1.1600x; 1.0067x over previous
//
#include <hip/hip_runtime.h>
#include <math.h>

// InstantNGP-style hash-grid encoder, 16 levels, FEAT=2, B=2M points.
//   dense levels 0..4 (res^3 <= 2^19), hashed levels 5..15 (size = 2^19 each)
//
// Measured model (r3-r8): fully-divergent gathers cost ~127 cyc per
// wave-instruction per CU (cache-level-independent L2/L3, width-independent
// <=16B, exec-mask-independent). Fine kernels (8x 8B gathers/pt from the
// pristine f32 table, 8B NT ws store) sit exactly at this floor: 51.6us/level.
// Structure:
//   - 11x fine_level_kernel -> fws slices (proven config, untouched)
//   - convert_dense_kernel  -> paired bf16 dense table E (x-pair in one 8B)
//   - dense_merge_kernel    -> 5 dense levels (level 0 from LDS, 1-4 from E,
//     4x 8B gathers each) + reads 11 fws slices + writes [B,32] out directly.
//     Streaming (456MB) overlaps the TA-request-bound gathers.
#define NLEVELS 16
#define BEGIN_FAST 5
#define P2 2654435761u
#define P3 805459861u
#define FAST_MASK 524287u
#define DENSE_TOTAL 330952u

constexpr unsigned kRes[NLEVELS] = {16u, 23u, 31u, 43u, 59u, 81u, 112u, 154u, 213u, 295u, 407u, 562u, 777u, 1073u, 1483u, 2048u};
constexpr unsigned kSize[NLEVELS] = {
    4096u, 12168u, 29792u, 79512u, 205384u,
    524288u, 524288u, 524288u, 524288u, 524288u, 524288u,
    524288u, 524288u, 524288u, 524288u, 524288u};
constexpr unsigned kOffset[NLEVELS] = {
    0u,       4096u,    16264u,   46056u,   125568u,  330952u,
    855240u,  1379528u, 1903816u, 2428104u, 2952392u, 3476680u,
    4000968u, 4525256u, 5049544u, 5573832u};

struct Scales {
    float s[NLEVELS];
};

typedef float fvec2 __attribute__((ext_vector_type(2)));
typedef float fvec4 __attribute__((ext_vector_type(4)));
typedef unsigned uvec2 __attribute__((ext_vector_type(2)));

// pack two f32 -> bf16x2 (round-to-nearest-even), lo = a, hi = b
__device__ __forceinline__ unsigned bfpack(float a, float b) {
    unsigned ua = __float_as_uint(a);
    unsigned ub = __float_as_uint(b);
    ua = (ua + 0x7FFFu + ((ua >> 16) & 1u)) >> 16;
    ub = (ub + 0x7FFFu + ((ub >> 16) & 1u)) & 0xFFFF0000u;
    return ua | ub;
}
__device__ __forceinline__ float bf_lo(unsigned e) { return __uint_as_float(e << 16); }
__device__ __forceinline__ float bf_hi(unsigned e) { return __uint_as_float(e & 0xFFFF0000u); }

// ---- convert dense tables to paired bf16: E[j] = (Tbf[j], Tbf[(j+1)%size]) --
__global__ __launch_bounds__(256) void convert_dense_kernel(
    const float2* __restrict__ table,  // full f32 table
    uvec2* __restrict__ E,             // paired bf16 dense table [DENSE_TOTAL]
    int total)
{
    int j = blockIdx.x * 256 + threadIdx.x;
    if (j >= total) return;
    int l = 0;
    if (j >= (int)kOffset[1]) l = 1;
    if (j >= (int)kOffset[2]) l = 2;
    if (j >= (int)kOffset[3]) l = 3;
    if (j >= (int)kOffset[4]) l = 4;
    const unsigned jl = (unsigned)j - kOffset[l];
    const unsigned jn = (jl + 1u == kSize[l]) ? 0u : jl + 1u;
    const float2 t0 = table[kOffset[l] + jl];
    const float2 t1 = table[kOffset[l] + jn];
    uvec2 r = {bfpack(t0.x, t0.y), bfpack(t1.x, t1.y)};
    __builtin_nontemporal_store(r, E + j);
}

// ---------------- fine (hashed) level: EXACT proven 51.6us config ------------
__global__ __launch_bounds__(256) void fine_level_kernel(
    const float* __restrict__ positions,  // [B,3]
    const float2* __restrict__ tab,       // f32 table + level offset
    float2* __restrict__ wsl,             // ws slice [B], float2
    int B, float s)
{
    int p = blockIdx.x * 256 + threadIdx.x;
    if (p >= B) return;

    const float x = __builtin_nontemporal_load(positions + 3 * p + 0);
    const float y = __builtin_nontemporal_load(positions + 3 * p + 1);
    const float z = __builtin_nontemporal_load(positions + 3 * p + 2);

    const float px = x * s + 0.5f;
    const float py = y * s + 0.5f;
    const float pz = z * s + 0.5f;
    const float flx = floorf(px), fly = floorf(py), flz = floorf(pz);
    const float rx = px - flx, ry = py - fly, rz = pz - flz;
    const unsigned gx = (unsigned)flx;
    const unsigned gy = (unsigned)fly;
    const unsigned gz = (unsigned)flz;
    const float wx0 = 1.0f - rx, wy0 = 1.0f - ry, wz0 = 1.0f - rz;

    const unsigned hy0 = gy * P2, hy1 = hy0 + P2;
    const unsigned hz0 = gz * P3, hz1 = hz0 + P3;

    float ax = 0.0f, ay = 0.0f;
#pragma unroll
    for (int c = 0; c < 8; ++c) {
        const unsigned cx = (unsigned)(c & 1);
        const unsigned cy = (unsigned)((c >> 1) & 1);
        const unsigned cz = (unsigned)((c >> 2) & 1);
        const float w = (cx ? rx : wx0) * (cy ? ry : wy0) * (cz ? rz : wz0);
        const unsigned h = (gx + cx) ^ (cy ? hy1 : hy0) ^ (cz ? hz1 : hz0);
        const float2 t = tab[h & FAST_MASK];
        ax += w * t.x;
        ay += w * t.y;
    }
    fvec2 r = {ax, ay};
    __builtin_nontemporal_store(r, reinterpret_cast<fvec2*>(wsl) + p);
}

// ---- dense levels (L0 via LDS, L1-4 via E) + merge fws -> direct output -----
__global__ __launch_bounds__(256) void dense_merge_kernel(
    const float* __restrict__ positions,  // [B,3]
    const uvec2* __restrict__ E,          // paired bf16 dense table
    const float2* __restrict__ fws,       // [11][B] fine slices
    float* __restrict__ out,              // [B,32]
    int B, Scales sc)
{
    __shared__ uvec2 lds_E0[4096];        // level-0 paired table, 32KB
    for (int i = threadIdx.x; i < 4096; i += 256) {
        lds_E0[i] = E[i];
    }
    __syncthreads();

    const int p = blockIdx.x * 256 + threadIdx.x;
    if (p >= B) return;

    const float x = __builtin_nontemporal_load(positions + 3 * p + 0);
    const float y = __builtin_nontemporal_load(positions + 3 * p + 1);
    const float z = __builtin_nontemporal_load(positions + 3 * p + 2);

    float o[2 * NLEVELS];

#pragma unroll
    for (int l = 0; l < BEGIN_FAST; ++l) {
        const float s = sc.s[l];
        const float px = x * s + 0.5f;
        const float py = y * s + 0.5f;
        const float pz = z * s + 0.5f;
        const float flx = floorf(px), fly = floorf(py), flz = floorf(pz);
        const float rx = px - flx, ry = py - fly, rz = pz - flz;
        const unsigned gx = (unsigned)flx;
        const unsigned gy = (unsigned)fly;
        const unsigned gz = (unsigned)flz;
        const float wx0 = 1.0f - rx, wy0 = 1.0f - ry, wz0 = 1.0f - rz;

        const uvec2* tab = E + kOffset[l];
        const unsigned res = kRes[l];

        float ax = 0.0f, ay = 0.0f;
#pragma unroll
        for (int cc = 0; cc < 4; ++cc) {          // (cy, cz); x-pair in one 8B
            const unsigned cy = (unsigned)(cc & 1);
            const unsigned cz = (unsigned)(cc >> 1);
            const float wyz = (cy ? ry : wy0) * (cz ? rz : wz0);
            const unsigned h0 = gx + (gy + cy) * res + (gz + cz) * (res * res);
            const unsigned idx0 = h0 % kSize[l];
            const uvec2 q = (l == 0) ? lds_E0[idx0] : tab[idx0];
            ax += wyz * (wx0 * bf_lo(q.x) + rx * bf_lo(q.y));
            ay += wyz * (wx0 * bf_hi(q.x) + rx * bf_hi(q.y));
        }
        o[2 * l + 0] = ax;
        o[2 * l + 1] = ay;
    }

#pragma unroll
    for (int l = BEGIN_FAST; l < NLEVELS; ++l) {
        const fvec2 v = __builtin_nontemporal_load(
            reinterpret_cast<const fvec2*>(fws) + (size_t)(l - BEGIN_FAST) * (size_t)B + p);
        o[2 * l + 0] = v.x;
        o[2 * l + 1] = v.y;
    }

    float* op = out + (size_t)p * (2 * NLEVELS);
#pragma unroll
    for (int i = 0; i < 8; ++i) {
        fvec4 v = {o[4 * i + 0], o[4 * i + 1], o[4 * i + 2], o[4 * i + 3]};
        *(reinterpret_cast<fvec4*>(op) + i) = v;
    }
}

// ---------------- fallback: monolithic f32 (if ws too small) -----------------
__global__ __launch_bounds__(256) void hash_encode_kernel(
    const float* __restrict__ positions,
    const float2* __restrict__ table,
    float* __restrict__ out,
    int B, Scales sc)
{
    int p = blockIdx.x * 256 + threadIdx.x;
    if (p >= B) return;

    const float x = positions[3 * p + 0];
    const float y = positions[3 * p + 1];
    const float z = positions[3 * p + 2];

    float o[2 * NLEVELS];

#pragma unroll
    for (int l = 0; l < NLEVELS; ++l) {
        const float s = sc.s[l];
        const float px = x * s + 0.5f;
        const float py = y * s + 0.5f;
        const float pz = z * s + 0.5f;
        const float flx = floorf(px), fly = floorf(py), flz = floorf(pz);
        const float rx = px - flx, ry = py - fly, rz = pz - flz;
        const unsigned gx = (unsigned)flx;
        const unsigned gy = (unsigned)fly;
        const unsigned gz = (unsigned)flz;
        const float wx0 = 1.0f - rx, wy0 = 1.0f - ry, wz0 = 1.0f - rz;

        float ax = 0.0f, ay = 0.0f;
#pragma unroll
        for (int c = 0; c < 8; ++c) {
            const unsigned cx = (unsigned)(c & 1);
            const unsigned cy = (unsigned)((c >> 1) & 1);
            const unsigned cz = (unsigned)((c >> 2) & 1);
            const unsigned pgx = gx + cx;
            const unsigned pgy = gy + cy;
            const unsigned pgz = gz + cz;
            const float w = (cx ? rx : wx0) * (cy ? ry : wy0) * (cz ? rz : wz0);
            unsigned h;
            if (l < BEGIN_FAST) {
                h = pgx + pgy * kRes[l] + pgz * (kRes[l] * kRes[l]);
            } else {
                h = pgx ^ (pgy * P2) ^ (pgz * P3);
            }
            const unsigned idx = (h % kSize[l]) + kOffset[l];
            const float2 t = table[idx];
            ax += w * t.x;
            ay += w * t.y;
        }
        o[2 * l + 0] = ax;
        o[2 * l + 1] = ay;
    }

    float* op = out + (size_t)p * (2 * NLEVELS);
#pragma unroll
    for (int i = 0; i < 8; ++i) {
        fvec4 v = {o[4 * i + 0], o[4 * i + 1], o[4 * i + 2], o[4 * i + 3]};
        *(reinterpret_cast<fvec4*>(op) + i) = v;
    }
}

extern "C" void kernel_launch(void* const* d_in, const int* in_sizes, int n_in,
                              void* d_out, int out_size, void* d_ws, size_t ws_size,
                              hipStream_t stream) {
    const float* positions = (const float*)d_in[0];
    const float2* table = (const float2*)d_in[1];
    float* out = (float*)d_out;

    const int B = in_sizes[0] / 3;

    Scales sc;
    const double log_b = log(2048.0 / 16.0) / (NLEVELS - 1);
    for (int l = 0; l < NLEVELS; ++l) {
        sc.s[l] = (float)(16.0 * exp((double)l * log_b) - 1.0);
    }

    const int blocks = (B + 255) / 256;

    // ws layout: [11 fine slices, 8B each][paired dense table E]
    const size_t fws_bytes = 11u * (size_t)B * sizeof(float2);        // 176 MB
    const size_t E_bytes = (size_t)DENSE_TOTAL * sizeof(uvec2);       // 2.65 MB
    const size_t ws_need = fws_bytes + E_bytes;

    if (ws_size >= ws_need) {
        float2* fws = (float2*)d_ws;
        uvec2* E = (uvec2*)((char*)d_ws + fws_bytes);

        convert_dense_kernel<<<((int)DENSE_TOTAL + 255) / 256, 256, 0, stream>>>(
            table, E, (int)DENSE_TOTAL);

        for (int l = BEGIN_FAST; l < NLEVELS; ++l) {
            fine_level_kernel<<<blocks, 256, 0, stream>>>(
                positions, table + kOffset[l],
                fws + (size_t)(l - BEGIN_FAST) * (size_t)B, B, sc.s[l]);
        }
        dense_merge_kernel<<<blocks, 256, 0, stream>>>(positions, E, fws, out, B, sc);
    } else {
        hash_encode_kernel<<<blocks, 256, 0, stream>>>(positions, table, out, B, sc);
    }
}